// Round 5
// baseline (172.837 us; speedup 1.0000x reference)
//
#include <hip/hip_runtime.h>
#include <hip/hip_fp16.h>

#define HH 256
#define WW 256
#define KK 81
#define PLANE (HH * WW)
#define SLK 10            // row AND col halo
#define TR 21             // tile rows: [ho-10, ho+10]
#define TC 150            // tile cols: 128-px strip + 10 halo each side + 2
#define TAB (TR * TC)     // 3150 cells

// Pack [B,3,H,W] fp32 -> [B,H,W] ushort4 of fp16 (c0,c1,c2,0): one 8 B cell
// carries all 3 color groups for a pixel.
__global__ __launch_bounds__(256) void pack_kernel(const float* __restrict__ in,
                                                   ushort4* __restrict__ img) {
    int idx = blockIdx.x * 256 + threadIdx.x;  // b*PLANE + pix
    int b = idx >> 16;
    int pix = idx & 0xFFFF;
    const float* base = in + (size_t)b * 3 * PLANE + pix;
    _Float16 h0 = (_Float16)base[0];
    _Float16 h1 = (_Float16)base[PLANE];
    _Float16 h2 = (_Float16)base[2 * PLANE];
    ushort4 u;
    u.x = __builtin_bit_cast(unsigned short, h0);
    u.y = __builtin_bit_cast(unsigned short, h1);
    u.z = __builtin_bit_cast(unsigned short, h2);
    u.w = 0;
    img[idx] = u;
}

__device__ __forceinline__ void acc3(float w, unsigned int pa, unsigned int pb,
                                     float& ax, float& ay, float& az) {
    __half2 ha = __builtin_bit_cast(__half2, pa);
    __half2 hb = __builtin_bit_cast(__half2, pb);
    ax = fmaf(w, __low2float(ha), ax);   // v_fma_mix_f32 (lo)
    ay = fmaf(w, __high2float(ha), ay);  // v_fma_mix_f32 (hi)
    az = fmaf(w, __low2float(hb), az);
}

// INSTRUCTION-DIET kernel (round 5). Block = 128-px half-row, 2 waves; every
// wave computes ALL 81 taps for its 64 px, so k is WAVE-UNIFORM:
//   - ky/kx/weight[k]/plane strides all live in SGPRs (s_load / s_add);
//     zero per-lane loop bookkeeping.
//   - offset/mask loads: uniform SGPR base + lane byte-offset -> no per-tap
//     64-bit VGPR pointer math.
//   - integer-shift trick: r0 = floor(dy) + (ky+6), c0 = floor(dx+wof) +
//     (kxi+6); fract(dy) == wy. No py/px adds, no yb/xb subs.
//   - TC=150 (<254) so both corner pairs are single ds_read2_b64 with
//     imm offsets {0,1} and {150,151}.
//   - no barriers in the k-loop, no cross-wave reduction (direct store).
//   - escapes (|offset| > ~7, essentially never): sticky per-lane flag,
//     exact global clamped+masked redo loop at the end.
// ~45 VALU + 2 LDS + 3 VMEM per tap (vs ~110 VALU in rounds 0-4).
__global__ __launch_bounds__(128, 3) void dcn_kernel(
    const ushort4* __restrict__ img,
    const float* __restrict__ offset,
    const float* __restrict__ mask,
    const float* __restrict__ weight,
    const float* __restrict__ bias,
    float* __restrict__ out) {
    __shared__ uint2 tile[TAB];            // 25200 B zero-padded fp16 image

    const int t = threadIdx.x;             // local col in [0,128)
    const int b = blockIdx.y;
    const int ho = blockIdx.x >> 1;        // output row
    const int xo = (blockIdx.x & 1) * 128; // strip origin col
    const int yb = ho - SLK;
    const ushort4* ib = img + (size_t)b * PLANE;

    // ---- stage zero-padded tile: 3150 cells, 25 iters of 128 threads ----
    for (int i = 0; i < 25; ++i) {
        int cid = t + i * 128;
        if (cid < TAB) {
            int r = cid / TC;
            int c = cid - r * TC;
            int iy = yb + r;
            int ix = xo - SLK + c;
            unsigned int pa = 0, pb = 0;
            if (((unsigned)iy < (unsigned)HH) & ((unsigned)ix < (unsigned)WW)) {
                ushort4 u = ib[iy * WW + ix];
                pa = (unsigned int)u.x | ((unsigned int)u.y << 16);
                pb = (unsigned int)u.z;
            }
            tile[cid] = make_uint2(pa, pb);
        }
    }
    __syncthreads();

    // uniform row bases; per-lane part is just +t (SGPR base + VGPR offset)
    const float* orow = offset + (size_t)b * 2 * KK * PLANE + (size_t)ho * WW + xo;
    const float* mrow = mask + (size_t)b * KK * PLANE + (size_t)ho * WW + xo;

    const float wof = (float)t;
    float ax = 0.f, ay = 0.f, az = 0.f;
    bool escaped = false;

    for (int ky = 0; ky < 9; ++ky) {
        const int rshift = ky + (SLK - 4);            // uniform (SGPR)
#pragma unroll
        for (int kxi = 0; kxi < 9; ++kxi) {
            const int k = ky * 9 + kxi;               // uniform
            float dy = orow[(size_t)(2 * k) * PLANE + t];
            float dx = orow[(size_t)(2 * k + 1) * PLANE + t];
            float m = mrow[(size_t)k * PLANE + t];
            float wk = weight[k];                     // s_load

            float yf = floorf(dy);
            float wy = dy - yf;                       // fract(dy) == fract(py)
            int r0 = (int)yf + rshift;                // floor(py) - yb

            float px = dx + wof;
            float xf = floorf(px);
            float wx = px - xf;
            int c0 = (int)xf + (kxi + (SLK - 4));     // floor(px) - xb (local)

            bool ok = ((unsigned)r0 < (unsigned)(TR - 1)) &
                      ((unsigned)c0 < (unsigned)(TC - 1));
            escaped |= !ok;
            float mw = (ok ? m : 0.f) * wk;           // cndmask; zero kills tap

            float w1y = wy * mw, w0y = mw - w1y;      // validity via data
            float u1 = 1.f - wx;
            float w00 = w0y * u1, w01 = w0y * wx;
            float w10 = w1y * u1, w11 = w1y * wx;

            int r0c = min(max(r0, 0), TR - 2);        // LDS read always safe
            int c0c = min(max(c0, 0), TC - 2);
            const uint2* p = &tile[r0c * TC + c0c];
            uint2 q00 = p[0];
            uint2 q01 = p[1];                         // ds_read2_b64 {0,1}
            uint2 q10 = p[TC];
            uint2 q11 = p[TC + 1];                    // ds_read2_b64 {150,151}

            acc3(w00, q00.x, q00.y, ax, ay, az);
            acc3(w01, q01.x, q01.y, ax, ay, az);
            acc3(w10, q10.x, q10.y, ax, ay, az);
            acc3(w11, q11.x, q11.y, ax, ay, az);
        }
    }

    // ---- rare escapes: exact clamped + validity-masked global redo ----
    if (__builtin_expect(escaped, 0)) {
#pragma unroll 1
        for (int k = 0; k < KK; ++k) {
            int ky = k / 9;
            int kxi = k - ky * 9;
            float dy = orow[(size_t)(2 * k) * PLANE + t];
            float dx = orow[(size_t)(2 * k + 1) * PLANE + t];
            float m = mrow[(size_t)k * PLANE + t];

            float yf = floorf(dy);
            int r0 = (int)yf + ky + (SLK - 4);
            float px = dx + wof;
            float xf = floorf(px);
            int c0 = (int)xf + kxi + (SLK - 4);
            bool ok = ((unsigned)r0 < (unsigned)(TR - 1)) &
                      ((unsigned)c0 < (unsigned)(TC - 1));
            if (ok) continue;                         // pass 1 handled it

            // absolute coords, zero-pad semantics
            float wy = dy - yf;
            float wx = px - xf;
            int y0 = (int)yf + ho - 4 + ky;
            int x0 = (int)xf + xo + kxi - 4;
            int y1 = y0 + 1, x1 = x0 + 1;
            float mw = m * weight[k];
            float va0 = ((unsigned)y0 < (unsigned)HH) ? 1.f : 0.f;
            float va1 = ((unsigned)y1 < (unsigned)HH) ? 1.f : 0.f;
            float vb0 = ((unsigned)x0 < (unsigned)WW) ? 1.f : 0.f;
            float vb1 = ((unsigned)x1 < (unsigned)WW) ? 1.f : 0.f;
            float w1y = wy * mw, w0y = mw - w1y;
            float w00 = w0y * (1.f - wx) * va0 * vb0;
            float w01 = w0y * wx * va0 * vb1;
            float w10 = w1y * (1.f - wx) * va1 * vb0;
            float w11 = w1y * wx * va1 * vb1;
            int y0c = min(max(y0, 0), HH - 1);
            int y1c = min(max(y1, 0), HH - 1);
            int x0c = min(max(x0, 0), WW - 1);
            int x1c = min(max(x1, 0), WW - 1);
            ushort4 g00 = ib[y0c * WW + x0c];
            ushort4 g01 = ib[y0c * WW + x1c];
            ushort4 g10 = ib[y1c * WW + x0c];
            ushort4 g11 = ib[y1c * WW + x1c];
            acc3(w00, (unsigned int)g00.x | ((unsigned int)g00.y << 16), g00.z, ax, ay, az);
            acc3(w01, (unsigned int)g01.x | ((unsigned int)g01.y << 16), g01.z, ax, ay, az);
            acc3(w10, (unsigned int)g10.x | ((unsigned int)g10.y << 16), g10.z, ax, ay, az);
            acc3(w11, (unsigned int)g11.x | ((unsigned int)g11.y << 16), g11.z, ax, ay, az);
        }
    }

    // ---- direct write-out ----
    float bs = bias[0];
    float* ob = out + (size_t)b * 3 * PLANE + (size_t)ho * WW + xo + t;
    ob[0] = ax + bs;
    ob[PLANE] = ay + bs;
    ob[2 * PLANE] = az + bs;
}

extern "C" void kernel_launch(void* const* d_in, const int* in_sizes, int n_in,
                              void* d_out, int out_size, void* d_ws, size_t ws_size,
                              hipStream_t stream) {
    const float* input = (const float*)d_in[0];
    const float* offset = (const float*)d_in[1];
    const float* mask = (const float*)d_in[2];
    const float* weight = (const float*)d_in[3];
    const float* bias = (const float*)d_in[4];
    float* out = (float*)d_out;

    const int B = in_sizes[0] / (3 * PLANE);  // 2
    ushort4* img = (ushort4*)d_ws;            // 1 MB packed fp16 image

    pack_kernel<<<B * PLANE / 256, 256, 0, stream>>>(input, img);
    dim3 grid(HH * 2, B);                     // 2 half-row blocks per row
    dcn_kernel<<<grid, 128, 0, stream>>>(img, offset, mask, weight, bias, out);
}